// Round 2
// baseline (2996.498 us; speedup 1.0000x reference)
//
#include <hip/hip_runtime.h>

typedef unsigned short u16;
typedef __bf16 bf16x8 __attribute__((ext_vector_type(8)));
typedef float f32x4 __attribute__((ext_vector_type(4)));

#define HEADS 16
#define DHEAD 64
#define DIM 1024
#define NTOK 2048
#define BATCH 4
#define CTXD 768
#define SCROSS 77
#define FFIN 4096

__device__ inline float bf2f(u16 v) { return __uint_as_float(((unsigned)v) << 16); }
__device__ inline u16 f2bf(float f) {
    unsigned u = __float_as_uint(f);
    unsigned r = u + 0x7fffu + ((u >> 16) & 1u);
    return (u16)(r >> 16);
}
__device__ inline f32x4 f4zero() { f32x4 v; v[0]=0.f; v[1]=0.f; v[2]=0.f; v[3]=0.f; return v; }
__device__ inline bf16x8 as_bf16x8(uint4 u) { union { uint4 a; bf16x8 b; } c; c.a = u; return c.b; }

// ---------------- LayerNorm: fp32 in, bf16 out. One block per row of 1024. ----------------
__global__ __launch_bounds__(256) void ln_k(const float* __restrict__ X, const float* __restrict__ G,
                                            const float* __restrict__ Bt, u16* __restrict__ Y) {
    int row = blockIdx.x;
    int t = threadIdx.x;
    int w = t >> 6, lane = t & 63;
    float4 xv = *(const float4*)(X + (size_t)row * DIM + t * 4);
    float s = xv.x + xv.y + xv.z + xv.w;
    float s2 = xv.x*xv.x + xv.y*xv.y + xv.z*xv.z + xv.w*xv.w;
    for (int off = 1; off < 64; off <<= 1) {
        s  += __shfl_xor(s,  off, 64);
        s2 += __shfl_xor(s2, off, 64);
    }
    __shared__ float rs[4], rs2[4];
    if (lane == 0) { rs[w] = s; rs2[w] = s2; }
    __syncthreads();
    float S_ = rs[0] + rs[1] + rs[2] + rs[3];
    float S2_ = rs2[0] + rs2[1] + rs2[2] + rs2[3];
    float mean = S_ * (1.0f / DIM);
    float var = fmaxf(S2_ * (1.0f / DIM) - mean * mean, 0.f);
    float rstd = rsqrtf(var + 1e-5f);
    int col = t * 4;
    float4 g = *(const float4*)(G + col);
    float4 b = *(const float4*)(Bt + col);
    float y0 = (xv.x - mean) * rstd * g.x + b.x;
    float y1 = (xv.y - mean) * rstd * g.y + b.y;
    float y2 = (xv.z - mean) * rstd * g.z + b.z;
    float y3 = (xv.w - mean) * rstd * g.w + b.w;
    uint2 o;
    o.x = (unsigned)f2bf(y0) | ((unsigned)f2bf(y1) << 16);
    o.y = (unsigned)f2bf(y2) | ((unsigned)f2bf(y3) << 16);
    *(uint2*)(Y + (size_t)row * DIM + col) = o;
}

// ---------------- GEMM: C[M,N] = A[M,K] * B[K,N] (+bias +resid) ----------------
// A: bf16(u16) or fp32 (converted to bf16 in staging). B: fp32 weights (converted in staging).
// C: bf16 or fp32. 64x64 tile, BK=32, 256 threads = 4 waves; wave w does rows [w*16, w*16+16).
template<typename TA, typename TC, bool RESID>
__global__ __launch_bounds__(256) void gemm64(const TA* __restrict__ A, const float* __restrict__ B,
                                              const float* __restrict__ bias, const float* resid,
                                              TC* C, int M, int N, int K) {
    __shared__ __align__(16) u16 As[64][32];
    __shared__ __align__(16) u16 Bs[64][40];  // transposed: Bs[n][k], padded ld=40
    int m0 = blockIdx.x * 64, n0 = blockIdx.y * 64;
    int t = threadIdx.x;
    int w = t >> 6, lane = t & 63;
    int quad = lane >> 4, l16 = lane & 15;
    f32x4 acc[4];
    #pragma unroll
    for (int i = 0; i < 4; i++) acc[i] = f4zero();
    int ar = t >> 2, ac = (t & 3) * 8;     // A stage: 64 rows x 32 cols, 8 elems/thread
    int br = t >> 3, bc = (t & 7) * 8;     // B stage: 32 krows x 64 ncols, 8 elems/thread
    for (int k0 = 0; k0 < K; k0 += 32) {
        bool arow_ok = (m0 + ar) < M;
        if constexpr (__is_same(TA, u16)) {
            uint4 av;
            if (arow_ok) av = *(const uint4*)(A + (size_t)(m0 + ar) * K + k0 + ac);
            else { av.x = av.y = av.z = av.w = 0u; }
            *(uint4*)(&As[ar][ac]) = av;
        } else {
            float4 a0, a1;
            a0.x=a0.y=a0.z=a0.w=0.f; a1 = a0;
            if (arow_ok) {
                const float* ap = A + (size_t)(m0 + ar) * K + k0 + ac;
                a0 = *(const float4*)ap;
                a1 = *(const float4*)(ap + 4);
            }
            union { uint4 u; u16 e[8]; } pu;
            pu.e[0]=f2bf(a0.x); pu.e[1]=f2bf(a0.y); pu.e[2]=f2bf(a0.z); pu.e[3]=f2bf(a0.w);
            pu.e[4]=f2bf(a1.x); pu.e[5]=f2bf(a1.y); pu.e[6]=f2bf(a1.z); pu.e[7]=f2bf(a1.w);
            *(uint4*)(&As[ar][ac]) = pu.u;
        }
        {
            const float* bp = B + (size_t)(k0 + br) * N + n0 + bc;
            float4 b0 = *(const float4*)bp;
            float4 b1 = *(const float4*)(bp + 4);
            Bs[bc + 0][br] = f2bf(b0.x); Bs[bc + 1][br] = f2bf(b0.y);
            Bs[bc + 2][br] = f2bf(b0.z); Bs[bc + 3][br] = f2bf(b0.w);
            Bs[bc + 4][br] = f2bf(b1.x); Bs[bc + 5][br] = f2bf(b1.y);
            Bs[bc + 6][br] = f2bf(b1.z); Bs[bc + 7][br] = f2bf(b1.w);
        }
        __syncthreads();
        bf16x8 af = as_bf16x8(*(const uint4*)(&As[w * 16 + l16][quad * 8]));
        #pragma unroll
        for (int nt = 0; nt < 4; nt++) {
            bf16x8 bfv = as_bf16x8(*(const uint4*)(&Bs[nt * 16 + l16][quad * 8]));
            acc[nt] = __builtin_amdgcn_mfma_f32_16x16x32_bf16(af, bfv, acc[nt], 0, 0, 0);
        }
        __syncthreads();
    }
    #pragma unroll
    for (int nt = 0; nt < 4; nt++) {
        int gn = n0 + nt * 16 + l16;
        float bv = bias ? bias[gn] : 0.f;
        #pragma unroll
        for (int r = 0; r < 4; r++) {
            int gm = m0 + w * 16 + quad * 4 + r;
            if (gm < M) {
                float v = acc[nt][r] + bv;
                if constexpr (RESID) v += resid[(size_t)gm * N + gn];
                if constexpr (__is_same(TC, u16)) C[(size_t)gm * N + gn] = f2bf(v);
                else                              C[(size_t)gm * N + gn] = v;
            }
        }
    }
}

// ---------------- Flash attention (bf16 in/out): block = (b,h) x 64-q tile; 4 waves x 16 q rows ----
// Q/O: [B*NTOK, DIM] rows; K,V: [B*S, DIM] rows. In-place O==Q is safe (each block reads its own
// Q tile into registers at start, writes the identical region at the end; blocks are disjoint).
__global__ __launch_bounds__(256) void attn_k(const u16* Q, const u16* __restrict__ K,
                                              const u16* __restrict__ V, u16* O, int S) {
    __shared__ __align__(16) u16 Vt[64][40];      // Vt[d][k], padded
    __shared__ __align__(16) u16 Pb[4][16][32];   // per-wave P tile
    int bh = blockIdx.x;
    int b = bh >> 4, h = bh & 15;
    int q0 = blockIdx.y * 64;
    int t = threadIdx.x;
    int w = t >> 6, lane = t & 63;
    int quad = lane >> 4, l16 = lane & 15;
    const u16* Qp = Q + ((size_t)b * NTOK + q0) * DIM + h * DHEAD;
    const u16* Kp = K + (size_t)b * S * DIM + h * DHEAD;
    const u16* Vp = V + (size_t)b * S * DIM + h * DHEAD;
    bf16x8 qf[2];
    #pragma unroll
    for (int ds = 0; ds < 2; ds++)
        qf[ds] = as_bf16x8(*(const uint4*)(Qp + (size_t)(w * 16 + l16) * DIM + ds * 32 + quad * 8));
    float m_r[4], l_r[4];
    f32x4 o_acc[4];
    #pragma unroll
    for (int r = 0; r < 4; r++) { m_r[r] = -1e30f; l_r[r] = 0.f; }
    #pragma unroll
    for (int dt = 0; dt < 4; dt++) o_acc[dt] = f4zero();
    int kr = t >> 3, dc = (t & 7) * 8;  // V stage: 32 keys x 64 d
    int nkt = (S + 31) / 32;
    const float scale = 0.125f;
    for (int kt = 0; kt < nkt; kt++) {
        __syncthreads();
        {   // stage V transposed
            int key = kt * 32 + kr;
            uint4 vv; vv.x = vv.y = vv.z = vv.w = 0u;
            if (key < S) vv = *(const uint4*)(Vp + (size_t)key * DIM + dc);
            union { uint4 u; u16 e[8]; } vu; vu.u = vv;
            #pragma unroll
            for (int i = 0; i < 8; i++) Vt[dc + i][kr] = vu.e[i];
        }
        // scores: two 16-key subtiles
        f32x4 sc[2];
        #pragma unroll
        for (int sub = 0; sub < 2; sub++) {
            f32x4 s = f4zero();
            int krow = kt * 32 + sub * 16 + l16;
            bool kvalid = krow < S;
            #pragma unroll
            for (int ds = 0; ds < 2; ds++) {
                uint4 kv; kv.x = kv.y = kv.z = kv.w = 0u;
                if (kvalid) kv = *(const uint4*)(Kp + (size_t)krow * DIM + ds * 32 + quad * 8);
                s = __builtin_amdgcn_mfma_f32_16x16x32_bf16(qf[ds], as_bf16x8(kv), s, 0, 0, 0);
            }
            sc[sub] = s;
        }
        bool v0 = (kt * 32 + l16) < S;
        bool v1 = (kt * 32 + 16 + l16) < S;
        #pragma unroll
        for (int r = 0; r < 4; r++) {
            float s0 = v0 ? sc[0][r] * scale : -1e30f;
            float s1 = v1 ? sc[1][r] * scale : -1e30f;
            float rm = fmaxf(s0, s1);
            for (int off = 1; off < 16; off <<= 1) rm = fmaxf(rm, __shfl_xor(rm, off, 64));
            float mnew = fmaxf(m_r[r], rm);
            float alpha = __expf(m_r[r] - mnew);
            float p0 = __expf(s0 - mnew);
            float p1 = __expf(s1 - mnew);
            float rsum = p0 + p1;
            for (int off = 1; off < 16; off <<= 1) rsum += __shfl_xor(rsum, off, 64);
            l_r[r] = l_r[r] * alpha + rsum;
            m_r[r] = mnew;
            #pragma unroll
            for (int dt = 0; dt < 4; dt++) o_acc[dt][r] *= alpha;
            Pb[w][quad * 4 + r][l16]      = f2bf(p0);
            Pb[w][quad * 4 + r][16 + l16] = f2bf(p1);
        }
        __syncthreads();
        bf16x8 pf = as_bf16x8(*(const uint4*)(&Pb[w][l16][quad * 8]));
        #pragma unroll
        for (int dt = 0; dt < 4; dt++) {
            bf16x8 vf = as_bf16x8(*(const uint4*)(&Vt[dt * 16 + l16][quad * 8]));
            o_acc[dt] = __builtin_amdgcn_mfma_f32_16x16x32_bf16(pf, vf, o_acc[dt], 0, 0, 0);
        }
    }
    #pragma unroll
    for (int r = 0; r < 4; r++) {
        float invl = (l_r[r] > 0.f) ? (1.f / l_r[r]) : 0.f;
        int gq = q0 + w * 16 + quad * 4 + r;
        #pragma unroll
        for (int dt = 0; dt < 4; dt++) {
            O[((size_t)b * NTOK + gq) * DIM + h * DHEAD + dt * 16 + l16] = f2bf(o_acc[dt][r] * invl);
        }
    }
}

// ---------------- GEGLU: out[r,c] = a * gelu_exact(gate); H bf16 [rows, 8192], G bf16 [rows, 4096] ----
__global__ __launch_bounds__(256) void geglu_k(const u16* __restrict__ H, u16* __restrict__ G) {
    int c = blockIdx.x * 256 + threadIdx.x;
    size_t row = blockIdx.y;
    float a = bf2f(H[row * (2 * FFIN) + c]);
    float g = bf2f(H[row * (2 * FFIN) + FFIN + c]);
    float out = a * (0.5f * g * (1.f + erff(g * 0.70710678118654752f)));
    G[row * FFIN + c] = f2bf(out);
}

extern "C" void kernel_launch(void* const* d_in, const int* in_sizes, int n_in,
                              void* d_out, int out_size, void* d_ws, size_t ws_size,
                              hipStream_t stream) {
    const float* x   = (const float*)d_in[0];
    const float* ctx = (const float*)d_in[1];
    const float* Wq1 = (const float*)d_in[2];
    const float* Wk1 = (const float*)d_in[3];
    const float* Wv1 = (const float*)d_in[4];
    const float* Wo1 = (const float*)d_in[5];
    const float* bo1 = (const float*)d_in[6];
    const float* Wq2 = (const float*)d_in[7];
    const float* Wk2 = (const float*)d_in[8];
    const float* Wv2 = (const float*)d_in[9];
    const float* Wo2 = (const float*)d_in[10];
    const float* bo2 = (const float*)d_in[11];
    const float* Wp  = (const float*)d_in[12];
    const float* bp  = (const float*)d_in[13];
    const float* Wf  = (const float*)d_in[14];
    const float* bfb = (const float*)d_in[15];
    const float* g1  = (const float*)d_in[16];
    const float* b1  = (const float*)d_in[17];
    const float* g2  = (const float*)d_in[18];
    const float* b2  = (const float*)d_in[19];
    const float* g3  = (const float*)d_in[20];
    const float* b3  = (const float*)d_in[21];
    float* out = (float*)d_out;

    const size_t R = (size_t)BATCH * NTOK * DIM;  // 8388608 elems
    u16* ws = (u16*)d_ws;
    // bf16 slots (each R u16 = 16.8 MB):
    u16* P  = ws;          // LN outputs
    u16* Qb = ws + R;      // Q / attn-out (in-place)
    u16* Ks = ws + 2 * R;  // self K
    u16* Vs = ws + 3 * R;  // self V
    // X1 (fp32 residual after self-attn) overlays Ks+Vs once they're dead:
    float* X1 = (float*)(ws + 2 * R);
    // FF chunk buffers overlay X1's region once X1 is dead:
    u16* hb = ws + 2 * R;  // [1024, 8192] bf16
    u16* gb = ws + 3 * R;  // [1024, 4096] bf16
    // small cross-attn K/V (308 x 1024 each):
    u16* Kc = ws + 4 * R;
    u16* Vc = Kc + (size_t)BATCH * SCROSS * DIM;

    const int M = BATCH * NTOK;  // 8192
    const int Mc = BATCH * SCROSS;  // 308
    dim3 blk(256);

    // --- self attention ---
    ln_k<<<dim3(M), blk, 0, stream>>>(x, g1, b1, P);
    gemm64<u16, u16, false><<<dim3(M / 64, DIM / 64), blk, 0, stream>>>(P, Wq1, nullptr, nullptr, Qb, M, DIM, DIM);
    gemm64<u16, u16, false><<<dim3(M / 64, DIM / 64), blk, 0, stream>>>(P, Wk1, nullptr, nullptr, Ks, M, DIM, DIM);
    gemm64<u16, u16, false><<<dim3(M / 64, DIM / 64), blk, 0, stream>>>(P, Wv1, nullptr, nullptr, Vs, M, DIM, DIM);
    attn_k<<<dim3(BATCH * HEADS, NTOK / 64), blk, 0, stream>>>(Qb, Ks, Vs, Qb, NTOK);
    gemm64<u16, float, true><<<dim3(M / 64, DIM / 64), blk, 0, stream>>>(Qb, Wo1, bo1, x, X1, M, DIM, DIM);

    // --- cross attention ---
    ln_k<<<dim3(M), blk, 0, stream>>>(X1, g2, b2, P);
    gemm64<u16, u16, false><<<dim3(M / 64, DIM / 64), blk, 0, stream>>>(P, Wq2, nullptr, nullptr, Qb, M, DIM, DIM);
    gemm64<float, u16, false><<<dim3((Mc + 63) / 64, DIM / 64), blk, 0, stream>>>(ctx, Wk2, nullptr, nullptr, Kc, Mc, DIM, CTXD);
    gemm64<float, u16, false><<<dim3((Mc + 63) / 64, DIM / 64), blk, 0, stream>>>(ctx, Wv2, nullptr, nullptr, Vc, Mc, DIM, CTXD);
    attn_k<<<dim3(BATCH * HEADS, NTOK / 64), blk, 0, stream>>>(Qb, Kc, Vc, Qb, SCROSS);
    gemm64<u16, float, true><<<dim3(M / 64, DIM / 64), blk, 0, stream>>>(Qb, Wo2, bo2, X1, out, M, DIM, DIM);

    // --- GEGLU FF (8 chunks of 1024 rows; out doubles as x2 residual, consumed in-place) ---
    ln_k<<<dim3(M), blk, 0, stream>>>(out, g3, b3, P);
    const int chunkM = 1024;
    for (int c0 = 0; c0 < M; c0 += chunkM) {
        gemm64<u16, u16, false><<<dim3(chunkM / 64, (2 * FFIN) / 64), blk, 0, stream>>>(
            P + (size_t)c0 * DIM, Wp, bp, nullptr, hb, chunkM, 2 * FFIN, DIM);
        geglu_k<<<dim3(FFIN / 256, chunkM), blk, 0, stream>>>(hb, gb);
        gemm64<u16, float, true><<<dim3(chunkM / 64, DIM / 64), blk, 0, stream>>>(
            gb, Wf, bfb, out + (size_t)c0 * DIM, out + (size_t)c0 * DIM, chunkM, DIM, FFIN);
    }
}

// Round 3
// 1312.123 us; speedup vs baseline: 2.2837x; 2.2837x over previous
//
#include <hip/hip_runtime.h>

typedef unsigned short u16;
typedef __bf16 bf16x8 __attribute__((ext_vector_type(8)));
typedef float f32x4 __attribute__((ext_vector_type(4)));

#define HEADS 16
#define DHEAD 64
#define DIM 1024
#define NTOK 2048
#define BATCH 4
#define CTXD 768
#define SCROSS 77
#define FFIN 4096

__device__ inline float bf2f(u16 v) { return __uint_as_float(((unsigned)v) << 16); }
__device__ inline u16 f2bf(float f) {
    unsigned u = __float_as_uint(f);
    unsigned r = u + 0x7fffu + ((u >> 16) & 1u);
    return (u16)(r >> 16);
}
__device__ inline f32x4 f4zero() { f32x4 v; v[0]=0.f; v[1]=0.f; v[2]=0.f; v[3]=0.f; return v; }
__device__ inline bf16x8 as_bf16x8(uint4 u) { union { uint4 a; bf16x8 b; } c; c.a = u; return c.b; }

// async global->LDS, 16B per lane; lds dest is wave-uniform base + lane*16
__device__ inline void gload_lds16(const u16* g, u16* l) {
    __builtin_amdgcn_global_load_lds((const __attribute__((address_space(1))) unsigned*)g,
                                     (__attribute__((address_space(3))) unsigned*)l, 16, 0, 0);
}

// ---------------- weight convert+transpose: W[K][N] fp32 -> WT[N][K] bf16 ----------------
__global__ __launch_bounds__(256) void wt_k(const float* __restrict__ W, u16* __restrict__ WT,
                                            int K, int N) {
    __shared__ u16 Ts[64][72];
    int k0 = blockIdx.x * 64, n0 = blockIdx.y * 64;
    int t = threadIdx.x;
    int r = t >> 2, c4 = (t & 3) * 16;
    const float* wp = W + (size_t)(k0 + r) * N + n0 + c4;
    #pragma unroll
    for (int j = 0; j < 4; j++) {
        float4 v = *(const float4*)(wp + j * 4);
        Ts[c4 + j * 4 + 0][r] = f2bf(v.x);
        Ts[c4 + j * 4 + 1][r] = f2bf(v.y);
        Ts[c4 + j * 4 + 2][r] = f2bf(v.z);
        Ts[c4 + j * 4 + 3][r] = f2bf(v.w);
    }
    __syncthreads();
    int n = t >> 2, kc = (t & 3) * 16;
    u16* op = WT + (size_t)(n0 + n) * K + k0 + kc;
    *(uint4*)op       = *(const uint4*)&Ts[n][kc];
    *(uint4*)(op + 8) = *(const uint4*)&Ts[n][kc + 8];
}

// ---------------- fp32 -> bf16 convert (ctx) ----------------
__global__ __launch_bounds__(256) void cvt_k(const float* __restrict__ X, u16* __restrict__ Y, int n4) {
    int i = blockIdx.x * 256 + threadIdx.x;
    if (i < n4) {
        float4 v = *(const float4*)(X + (size_t)i * 4);
        uint2 o;
        o.x = (unsigned)f2bf(v.x) | ((unsigned)f2bf(v.y) << 16);
        o.y = (unsigned)f2bf(v.z) | ((unsigned)f2bf(v.w) << 16);
        *(uint2*)(Y + (size_t)i * 4) = o;
    }
}

// ---------------- LayerNorm: fp32 in, bf16 out. One block per row of 1024. ----------------
__global__ __launch_bounds__(256) void ln_k(const float* __restrict__ X, const float* __restrict__ G,
                                            const float* __restrict__ Bt, u16* __restrict__ Y) {
    int row = blockIdx.x;
    int t = threadIdx.x;
    int w = t >> 6, lane = t & 63;
    float4 xv = *(const float4*)(X + (size_t)row * DIM + t * 4);
    float s = xv.x + xv.y + xv.z + xv.w;
    float s2 = xv.x*xv.x + xv.y*xv.y + xv.z*xv.z + xv.w*xv.w;
    for (int off = 1; off < 64; off <<= 1) {
        s  += __shfl_xor(s,  off, 64);
        s2 += __shfl_xor(s2, off, 64);
    }
    __shared__ float rs[4], rs2[4];
    if (lane == 0) { rs[w] = s; rs2[w] = s2; }
    __syncthreads();
    float S_ = rs[0] + rs[1] + rs[2] + rs[3];
    float S2_ = rs2[0] + rs2[1] + rs2[2] + rs2[3];
    float mean = S_ * (1.0f / DIM);
    float var = fmaxf(S2_ * (1.0f / DIM) - mean * mean, 0.f);
    float rstd = rsqrtf(var + 1e-5f);
    int col = t * 4;
    float4 g = *(const float4*)(G + col);
    float4 b = *(const float4*)(Bt + col);
    float y0 = (xv.x - mean) * rstd * g.x + b.x;
    float y1 = (xv.y - mean) * rstd * g.y + b.y;
    float y2 = (xv.z - mean) * rstd * g.z + b.z;
    float y3 = (xv.w - mean) * rstd * g.w + b.w;
    uint2 o;
    o.x = (unsigned)f2bf(y0) | ((unsigned)f2bf(y1) << 16);
    o.y = (unsigned)f2bf(y2) | ((unsigned)f2bf(y3) << 16);
    *(uint2*)(Y + (size_t)row * DIM + col) = o;
}

// ---------------- GEMM m97-style: C[M,N] = A[M,K] * BT[N,K]^T (+bias +resid) ----------------
// 128x128 tile, BK=32, 256 thr = 4 waves (2x2 of 64x64), global_load_lds staging.
template<typename TC, bool RESID>
__global__ __launch_bounds__(256) void gemm128(const u16* __restrict__ A, const u16* __restrict__ BT,
                                               const float* __restrict__ bias, const float* resid,
                                               TC* C, int M, int N, int K) {
    __shared__ __align__(16) u16 As[128 * 32];
    __shared__ __align__(16) u16 Bs[128 * 32];
    int m0 = blockIdx.x * 128, n0 = blockIdx.y * 128;
    int t = threadIdx.x;
    int w = t >> 6, lane = t & 63;
    int quad = lane >> 4, l16 = lane & 15;
    int mh = (w & 1) * 64, nh = (w >> 1) * 64;
    f32x4 acc[4][4];
    #pragma unroll
    for (int i = 0; i < 4; i++)
        #pragma unroll
        for (int j = 0; j < 4; j++) acc[i][j] = f4zero();
    int sr = t >> 2;           // staging row 0..63
    int sc8 = (t & 3) * 8;     // staging col (elems)
    int ra0 = min(m0 + sr, M - 1);
    int ra1 = min(m0 + sr + 64, M - 1);
    const u16* ga0 = A + (size_t)ra0 * K + sc8;
    const u16* ga1 = A + (size_t)ra1 * K + sc8;
    const u16* gb0 = BT + (size_t)(n0 + sr) * K + sc8;
    const u16* gb1 = BT + (size_t)(n0 + sr + 64) * K + sc8;
    u16* lA0 = &As[w * 512];
    u16* lA1 = &As[2048 + w * 512];
    u16* lB0 = &Bs[w * 512];
    u16* lB1 = &Bs[2048 + w * 512];
    for (int k0 = 0; k0 < K; k0 += 32) {
        __syncthreads();
        gload_lds16(ga0 + k0, lA0);
        gload_lds16(ga1 + k0, lA1);
        gload_lds16(gb0 + k0, lB0);
        gload_lds16(gb1 + k0, lB1);
        __syncthreads();
        bf16x8 af[4], bfv[4];
        #pragma unroll
        for (int i = 0; i < 4; i++) {
            af[i]  = as_bf16x8(*(const uint4*)&As[(mh + i * 16 + l16) * 32 + quad * 8]);
            bfv[i] = as_bf16x8(*(const uint4*)&Bs[(nh + i * 16 + l16) * 32 + quad * 8]);
        }
        #pragma unroll
        for (int i = 0; i < 4; i++)
            #pragma unroll
            for (int j = 0; j < 4; j++)
                acc[i][j] = __builtin_amdgcn_mfma_f32_16x16x32_bf16(af[i], bfv[j], acc[i][j], 0, 0, 0);
    }
    #pragma unroll
    for (int j = 0; j < 4; j++) {
        int gn = n0 + nh + j * 16 + l16;
        float bv = bias ? bias[gn] : 0.f;
        #pragma unroll
        for (int i = 0; i < 4; i++) {
            #pragma unroll
            for (int r = 0; r < 4; r++) {
                int gm = m0 + mh + i * 16 + quad * 4 + r;
                if (gm < M) {
                    float v = acc[i][j][r] + bv;
                    if constexpr (RESID) v += resid[(size_t)gm * N + gn];
                    if constexpr (__is_same(TC, u16)) C[(size_t)gm * N + gn] = f2bf(v);
                    else                              C[(size_t)gm * N + gn] = v;
                }
            }
        }
    }
}

// ---------------- Flash attention, 128-key tiles: block = (b,h) x 64-q rows; 4 waves ----------------
__global__ __launch_bounds__(256) void attn_k(const u16* Q, const u16* __restrict__ K,
                                              const u16* __restrict__ V, u16* O, int S) {
    __shared__ __align__(16) u16 Vt[64][136];     // Vt[d][key], pad 136 (272B rows)
    __shared__ __align__(16) u16 Pb[4][16][136];  // per-wave P tile [qrow][key]
    int bh = blockIdx.x;
    int b = bh >> 4, h = bh & 15;
    int q0 = blockIdx.y * 64;
    int t = threadIdx.x;
    int w = t >> 6, lane = t & 63;
    int quad = lane >> 4, l16 = lane & 15;
    const u16* Qp = Q + ((size_t)b * NTOK + q0) * DIM + h * DHEAD;
    const u16* Kp = K + (size_t)b * S * DIM + h * DHEAD;
    const u16* Vp = V + (size_t)b * S * DIM + h * DHEAD;
    bf16x8 qf[2];
    #pragma unroll
    for (int ds = 0; ds < 2; ds++)
        qf[ds] = as_bf16x8(*(const uint4*)(Qp + (size_t)(w * 16 + l16) * DIM + ds * 32 + quad * 8));
    float m_r[4], l_r[4];
    f32x4 o_acc[4];
    #pragma unroll
    for (int r = 0; r < 4; r++) { m_r[r] = -1e30f; l_r[r] = 0.f; }
    #pragma unroll
    for (int dt = 0; dt < 4; dt++) o_acc[dt] = f4zero();
    int vd = (t >> 5) * 8;   // d-base for V staging (bank-clean mapping)
    int vk = (t & 31) * 4;   // key-base
    const float scale = 0.125f;
    int nkt = (S + 127) / 128;
    for (int kt = 0; kt < nkt; kt++) {
        int kbase = kt * 128;
        bool full = (kbase + 128) <= S;
        __syncthreads();
        {   // stage V transposed: 4 keys x 8 d per thread, packed pair writes
            union { uint4 u; u16 e[8]; } vr[4];
            #pragma unroll
            for (int j = 0; j < 4; j++) {
                int key = min(kbase + vk + j, S - 1);
                vr[j].u = *(const uint4*)(Vp + (size_t)key * DIM + vd);
            }
            #pragma unroll
            for (int d = 0; d < 8; d++) {
                unsigned p01 = (unsigned)vr[0].e[d] | ((unsigned)vr[1].e[d] << 16);
                unsigned p23 = (unsigned)vr[2].e[d] | ((unsigned)vr[3].e[d] << 16);
                *(unsigned*)&Vt[vd + d][vk]     = p01;
                *(unsigned*)&Vt[vd + d][vk + 2] = p23;
            }
        }
        // QK^T: 8 subtiles of 16 keys
        f32x4 sc[8];
        #pragma unroll
        for (int sub = 0; sub < 8; sub++) {
            f32x4 s = f4zero();
            int krow = min(kbase + sub * 16 + l16, S - 1);
            const u16* kp = Kp + (size_t)krow * DIM + quad * 8;
            s = __builtin_amdgcn_mfma_f32_16x16x32_bf16(qf[0], as_bf16x8(*(const uint4*)kp), s, 0, 0, 0);
            s = __builtin_amdgcn_mfma_f32_16x16x32_bf16(qf[1], as_bf16x8(*(const uint4*)(kp + 32)), s, 0, 0, 0);
            sc[sub] = s;
        }
        // online softmax per q-row
        #pragma unroll
        for (int r = 0; r < 4; r++) {
            float sv[8];
            float rm = -1e30f;
            #pragma unroll
            for (int sub = 0; sub < 8; sub++) {
                float s = sc[sub][r] * scale;
                if (!full && (kbase + sub * 16 + l16) >= S) s = -1e30f;
                sv[sub] = s;
                rm = fmaxf(rm, s);
            }
            #pragma unroll
            for (int off = 1; off < 16; off <<= 1) rm = fmaxf(rm, __shfl_xor(rm, off, 64));
            float mnew = fmaxf(m_r[r], rm);
            float alpha = __expf(m_r[r] - mnew);
            float psum = 0.f;
            int prow = quad * 4 + r;
            #pragma unroll
            for (int sub = 0; sub < 8; sub++) {
                float p = __expf(sv[sub] - mnew);
                psum += p;
                Pb[w][prow][sub * 16 + l16] = f2bf(p);
            }
            #pragma unroll
            for (int off = 1; off < 16; off <<= 1) psum += __shfl_xor(psum, off, 64);
            l_r[r] = l_r[r] * alpha + psum;
            m_r[r] = mnew;
            #pragma unroll
            for (int dt = 0; dt < 4; dt++) o_acc[dt][r] *= alpha;
        }
        __syncthreads();
        // PV: P[16q x 128k] * V[128k x 64d]
        #pragma unroll
        for (int kk = 0; kk < 4; kk++) {
            bf16x8 pf = as_bf16x8(*(const uint4*)&Pb[w][l16][kk * 32 + quad * 8]);
            #pragma unroll
            for (int dt = 0; dt < 4; dt++) {
                bf16x8 vf = as_bf16x8(*(const uint4*)&Vt[dt * 16 + l16][kk * 32 + quad * 8]);
                o_acc[dt] = __builtin_amdgcn_mfma_f32_16x16x32_bf16(pf, vf, o_acc[dt], 0, 0, 0);
            }
        }
    }
    #pragma unroll
    for (int r = 0; r < 4; r++) {
        float invl = (l_r[r] > 0.f) ? (1.f / l_r[r]) : 0.f;
        int gq = q0 + w * 16 + quad * 4 + r;
        #pragma unroll
        for (int dt = 0; dt < 4; dt++) {
            O[((size_t)b * NTOK + gq) * DIM + h * DHEAD + dt * 16 + l16] = f2bf(o_acc[dt][r] * invl);
        }
    }
}

// ---------------- GEGLU: out[r,c] = a * gelu_exact(gate); H bf16 [rows,8192] -> G bf16 [rows,4096] ----
__global__ __launch_bounds__(256) void geglu_k(const u16* __restrict__ H, u16* __restrict__ G) {
    int c = blockIdx.x * 256 + threadIdx.x;
    size_t row = blockIdx.y;
    float a = bf2f(H[row * (2 * FFIN) + c]);
    float g = bf2f(H[row * (2 * FFIN) + FFIN + c]);
    float out = a * (0.5f * g * (1.f + erff(g * 0.70710678118654752f)));
    G[row * FFIN + c] = f2bf(out);
}

extern "C" void kernel_launch(void* const* d_in, const int* in_sizes, int n_in,
                              void* d_out, int out_size, void* d_ws, size_t ws_size,
                              hipStream_t stream) {
    const float* x   = (const float*)d_in[0];
    const float* ctx = (const float*)d_in[1];
    const float* Wq1 = (const float*)d_in[2];
    const float* Wk1 = (const float*)d_in[3];
    const float* Wv1 = (const float*)d_in[4];
    const float* Wo1 = (const float*)d_in[5];
    const float* bo1 = (const float*)d_in[6];
    const float* Wq2 = (const float*)d_in[7];
    const float* Wk2 = (const float*)d_in[8];
    const float* Wv2 = (const float*)d_in[9];
    const float* Wo2 = (const float*)d_in[10];
    const float* bo2 = (const float*)d_in[11];
    const float* Wp  = (const float*)d_in[12];
    const float* bp  = (const float*)d_in[13];
    const float* Wf  = (const float*)d_in[14];
    const float* bfb = (const float*)d_in[15];
    const float* g1  = (const float*)d_in[16];
    const float* b1  = (const float*)d_in[17];
    const float* g2  = (const float*)d_in[18];
    const float* b2  = (const float*)d_in[19];
    const float* g3  = (const float*)d_in[20];
    const float* b3  = (const float*)d_in[21];
    float* out = (float*)d_out;

    const int M = BATCH * NTOK;      // 8192
    const int Mc = BATCH * SCROSS;   // 308
    const size_t R = (size_t)M * DIM;
    u16* ws = (u16*)d_ws;
    size_t o = 0;
    u16* WqT1 = ws + o; o += (size_t)DIM * DIM;
    u16* WkT1 = ws + o; o += (size_t)DIM * DIM;
    u16* WvT1 = ws + o; o += (size_t)DIM * DIM;
    u16* WoT1 = ws + o; o += (size_t)DIM * DIM;
    u16* WqT2 = ws + o; o += (size_t)DIM * DIM;
    u16* WoT2 = ws + o; o += (size_t)DIM * DIM;
    u16* WkT2 = ws + o; o += (size_t)DIM * CTXD;
    u16* WvT2 = ws + o; o += (size_t)DIM * CTXD;
    u16* WpT  = ws + o; o += (size_t)(2 * FFIN) * DIM;
    u16* WfT  = ws + o; o += (size_t)DIM * FFIN;
    u16* ctxb = ws + o; o += (size_t)Mc * CTXD;
    u16* Kc   = ws + o; o += (size_t)Mc * DIM;
    u16* Vc   = ws + o; o += (size_t)Mc * DIM;
    u16* P    = ws + o; o += R;
    u16* Qb   = ws + o; o += R;
    u16* reg2 = ws + o; o += 2 * R;   // Ks,Vs -> X1(fp32) -> hb
    u16* Ks = reg2;
    u16* Vs = reg2 + R;
    float* X1 = (float*)reg2;
    u16* hb = reg2;
    size_t base_elems = o;
    size_t gbfull_elems = (size_t)M * FFIN;
    bool planA = ws_size >= (base_elems + gbfull_elems) * sizeof(u16);
    u16* gbF = ws + base_elems;  // plan A only

    dim3 blk(256);

    // --- weight conversions (fp32 -> bf16, transposed to [N][K]) ---
    wt_k<<<dim3(16, 16), blk, 0, stream>>>(Wq1, WqT1, DIM, DIM);
    wt_k<<<dim3(16, 16), blk, 0, stream>>>(Wk1, WkT1, DIM, DIM);
    wt_k<<<dim3(16, 16), blk, 0, stream>>>(Wv1, WvT1, DIM, DIM);
    wt_k<<<dim3(16, 16), blk, 0, stream>>>(Wo1, WoT1, DIM, DIM);
    wt_k<<<dim3(16, 16), blk, 0, stream>>>(Wq2, WqT2, DIM, DIM);
    wt_k<<<dim3(16, 16), blk, 0, stream>>>(Wo2, WoT2, DIM, DIM);
    wt_k<<<dim3(12, 16), blk, 0, stream>>>(Wk2, WkT2, CTXD, DIM);
    wt_k<<<dim3(12, 16), blk, 0, stream>>>(Wv2, WvT2, CTXD, DIM);
    wt_k<<<dim3(16, 128), blk, 0, stream>>>(Wp, WpT, DIM, 2 * FFIN);
    wt_k<<<dim3(64, 16), blk, 0, stream>>>(Wf, WfT, FFIN, DIM);
    cvt_k<<<dim3((Mc * CTXD / 4 + 255) / 256), blk, 0, stream>>>(ctx, ctxb, Mc * CTXD / 4);

    // --- self attention ---
    ln_k<<<dim3(M), blk, 0, stream>>>(x, g1, b1, P);
    gemm128<u16, false><<<dim3(M / 128, DIM / 128), blk, 0, stream>>>(P, WqT1, nullptr, nullptr, Qb, M, DIM, DIM);
    gemm128<u16, false><<<dim3(M / 128, DIM / 128), blk, 0, stream>>>(P, WkT1, nullptr, nullptr, Ks, M, DIM, DIM);
    gemm128<u16, false><<<dim3(M / 128, DIM / 128), blk, 0, stream>>>(P, WvT1, nullptr, nullptr, Vs, M, DIM, DIM);
    attn_k<<<dim3(BATCH * HEADS, NTOK / 64), blk, 0, stream>>>(Qb, Ks, Vs, Qb, NTOK);
    gemm128<float, true><<<dim3(M / 128, DIM / 128), blk, 0, stream>>>(Qb, WoT1, bo1, x, X1, M, DIM, DIM);

    // --- cross attention ---
    ln_k<<<dim3(M), blk, 0, stream>>>(X1, g2, b2, P);
    gemm128<u16, false><<<dim3(M / 128, DIM / 128), blk, 0, stream>>>(P, WqT2, nullptr, nullptr, Qb, M, DIM, DIM);
    gemm128<u16, false><<<dim3((Mc + 127) / 128, DIM / 128), blk, 0, stream>>>(ctxb, WkT2, nullptr, nullptr, Kc, Mc, DIM, CTXD);
    gemm128<u16, false><<<dim3((Mc + 127) / 128, DIM / 128), blk, 0, stream>>>(ctxb, WvT2, nullptr, nullptr, Vc, Mc, DIM, CTXD);
    attn_k<<<dim3(BATCH * HEADS, NTOK / 64), blk, 0, stream>>>(Qb, Kc, Vc, Qb, SCROSS);
    gemm128<float, true><<<dim3(M / 128, DIM / 128), blk, 0, stream>>>(Qb, WoT2, bo2, X1, out, M, DIM, DIM);

    // --- GEGLU FF ---
    ln_k<<<dim3(M), blk, 0, stream>>>(out, g3, b3, P);
    if (planA) {
        const int CH = 2048;   // hb = 2048x8192 bf16 = 33.5 MB fits reg2 exactly
        for (int c0 = 0; c0 < M; c0 += CH) {
            gemm128<u16, false><<<dim3(CH / 128, (2 * FFIN) / 128), blk, 0, stream>>>(
                P + (size_t)c0 * DIM, WpT, bp, nullptr, hb, CH, 2 * FFIN, DIM);
            geglu_k<<<dim3(FFIN / 256, CH), blk, 0, stream>>>(hb, gbF + (size_t)c0 * FFIN);
        }
        gemm128<float, true><<<dim3(M / 128, DIM / 128), blk, 0, stream>>>(
            gbF, WfT, bfb, out, out, M, DIM, FFIN);
    } else {
        const int CH = 1024;   // hb (16.8MB) + gb (8.4MB) both inside reg2
        u16* gb = reg2 + (size_t)CH * (2 * FFIN);
        for (int c0 = 0; c0 < M; c0 += CH) {
            gemm128<u16, false><<<dim3(CH / 128, (2 * FFIN) / 128), blk, 0, stream>>>(
                P + (size_t)c0 * DIM, WpT, bp, nullptr, hb, CH, 2 * FFIN, DIM);
            geglu_k<<<dim3(FFIN / 256, CH), blk, 0, stream>>>(hb, gb);
            gemm128<float, true><<<dim3(CH / 128, DIM / 128), blk, 0, stream>>>(
                gb, WfT, bfb, out + (size_t)c0 * DIM, out + (size_t)c0 * DIM, CH, DIM, FFIN);
        }
    }
}

// Round 4
// 1136.247 us; speedup vs baseline: 2.6372x; 1.1548x over previous
//
#include <hip/hip_runtime.h>

typedef unsigned short u16;
typedef __bf16 bf16x8 __attribute__((ext_vector_type(8)));
typedef float f32x4 __attribute__((ext_vector_type(4)));

#define HEADS 16
#define DHEAD 64
#define DIM 1024
#define NTOK 2048
#define BATCH 4
#define CTXD 768
#define SCROSS 77
#define FFIN 4096

__device__ inline float bf2f(u16 v) { return __uint_as_float(((unsigned)v) << 16); }
__device__ inline u16 f2bf(float f) {
    unsigned u = __float_as_uint(f);
    unsigned r = u + 0x7fffu + ((u >> 16) & 1u);
    return (u16)(r >> 16);
}
__device__ inline f32x4 f4zero() { f32x4 v; v[0]=0.f; v[1]=0.f; v[2]=0.f; v[3]=0.f; return v; }
__device__ inline bf16x8 as_bf16x8(uint4 u) { union { uint4 a; bf16x8 b; } c; c.a = u; return c.b; }

// async global->LDS, 16B per lane; lds dest is wave-uniform base + lane*16
__device__ inline void gload_lds16(const u16* g, u16* l) {
    __builtin_amdgcn_global_load_lds((const __attribute__((address_space(1))) unsigned*)g,
                                     (__attribute__((address_space(3))) unsigned*)l, 16, 0, 0);
}

// ---------------- weight convert+transpose: W[K][N] fp32 -> WT[N][K] bf16 (xscale) ----------------
__global__ __launch_bounds__(256) void wt_k(const float* __restrict__ W, u16* __restrict__ WT,
                                            int K, int N, float scale) {
    __shared__ u16 Ts[64][72];
    int k0 = blockIdx.x * 64, n0 = blockIdx.y * 64;
    int t = threadIdx.x;
    int r = t >> 2, c4 = (t & 3) * 16;
    const float* wp = W + (size_t)(k0 + r) * N + n0 + c4;
    #pragma unroll
    for (int j = 0; j < 4; j++) {
        float4 v = *(const float4*)(wp + j * 4);
        Ts[c4 + j * 4 + 0][r] = f2bf(v.x * scale);
        Ts[c4 + j * 4 + 1][r] = f2bf(v.y * scale);
        Ts[c4 + j * 4 + 2][r] = f2bf(v.z * scale);
        Ts[c4 + j * 4 + 3][r] = f2bf(v.w * scale);
    }
    __syncthreads();
    int n = t >> 2, kc = (t & 3) * 16;
    u16* op = WT + (size_t)(n0 + n) * K + k0 + kc;
    *(uint4*)op       = *(const uint4*)&Ts[n][kc];
    *(uint4*)(op + 8) = *(const uint4*)&Ts[n][kc + 8];
}

// ---------------- fp32 -> bf16 convert (ctx) ----------------
__global__ __launch_bounds__(256) void cvt_k(const float* __restrict__ X, u16* __restrict__ Y, int n4) {
    int i = blockIdx.x * 256 + threadIdx.x;
    if (i < n4) {
        float4 v = *(const float4*)(X + (size_t)i * 4);
        uint2 o;
        o.x = (unsigned)f2bf(v.x) | ((unsigned)f2bf(v.y) << 16);
        o.y = (unsigned)f2bf(v.z) | ((unsigned)f2bf(v.w) << 16);
        *(uint2*)(Y + (size_t)i * 4) = o;
    }
}

// ---------------- LayerNorm: fp32 in, bf16 out. One block per row of 1024. ----------------
__global__ __launch_bounds__(256) void ln_k(const float* __restrict__ X, const float* __restrict__ G,
                                            const float* __restrict__ Bt, u16* __restrict__ Y) {
    int row = blockIdx.x;
    int t = threadIdx.x;
    int w = t >> 6, lane = t & 63;
    float4 xv = *(const float4*)(X + (size_t)row * DIM + t * 4);
    float s = xv.x + xv.y + xv.z + xv.w;
    float s2 = xv.x*xv.x + xv.y*xv.y + xv.z*xv.z + xv.w*xv.w;
    for (int off = 1; off < 64; off <<= 1) {
        s  += __shfl_xor(s,  off, 64);
        s2 += __shfl_xor(s2, off, 64);
    }
    __shared__ float rs[4], rs2[4];
    if (lane == 0) { rs[w] = s; rs2[w] = s2; }
    __syncthreads();
    float S_ = rs[0] + rs[1] + rs[2] + rs[3];
    float S2_ = rs2[0] + rs2[1] + rs2[2] + rs2[3];
    float mean = S_ * (1.0f / DIM);
    float var = fmaxf(S2_ * (1.0f / DIM) - mean * mean, 0.f);
    float rstd = rsqrtf(var + 1e-5f);
    int col = t * 4;
    float4 g = *(const float4*)(G + col);
    float4 b = *(const float4*)(Bt + col);
    float y0 = (xv.x - mean) * rstd * g.x + b.x;
    float y1 = (xv.y - mean) * rstd * g.y + b.y;
    float y2 = (xv.z - mean) * rstd * g.z + b.z;
    float y3 = (xv.w - mean) * rstd * g.w + b.w;
    uint2 o;
    o.x = (unsigned)f2bf(y0) | ((unsigned)f2bf(y1) << 16);
    o.y = (unsigned)f2bf(y2) | ((unsigned)f2bf(y3) << 16);
    *(uint2*)(Y + (size_t)row * DIM + col) = o;
}

// ---------------- GEMM m97-style: C[M,N] = A[M,K] * BT[N,K]^T (+bias +resid) ----------------
template<typename TC, bool RESID>
__global__ __launch_bounds__(256) void gemm128(const u16* __restrict__ A, const u16* __restrict__ BT,
                                               const float* __restrict__ bias, const float* resid,
                                               TC* C, int M, int N, int K) {
    __shared__ __align__(16) u16 As[128 * 32];
    __shared__ __align__(16) u16 Bs[128 * 32];
    int m0 = blockIdx.x * 128, n0 = blockIdx.y * 128;
    int t = threadIdx.x;
    int w = t >> 6, lane = t & 63;
    int quad = lane >> 4, l16 = lane & 15;
    int mh = (w & 1) * 64, nh = (w >> 1) * 64;
    f32x4 acc[4][4];
    #pragma unroll
    for (int i = 0; i < 4; i++)
        #pragma unroll
        for (int j = 0; j < 4; j++) acc[i][j] = f4zero();
    int sr = t >> 2;
    int sc8 = (t & 3) * 8;
    int ra0 = min(m0 + sr, M - 1);
    int ra1 = min(m0 + sr + 64, M - 1);
    const u16* ga0 = A + (size_t)ra0 * K + sc8;
    const u16* ga1 = A + (size_t)ra1 * K + sc8;
    const u16* gb0 = BT + (size_t)(n0 + sr) * K + sc8;
    const u16* gb1 = BT + (size_t)(n0 + sr + 64) * K + sc8;
    u16* lA0 = &As[w * 512];
    u16* lA1 = &As[2048 + w * 512];
    u16* lB0 = &Bs[w * 512];
    u16* lB1 = &Bs[2048 + w * 512];
    for (int k0 = 0; k0 < K; k0 += 32) {
        __syncthreads();
        gload_lds16(ga0 + k0, lA0);
        gload_lds16(ga1 + k0, lA1);
        gload_lds16(gb0 + k0, lB0);
        gload_lds16(gb1 + k0, lB1);
        __syncthreads();
        bf16x8 af[4], bfv[4];
        #pragma unroll
        for (int i = 0; i < 4; i++) {
            af[i]  = as_bf16x8(*(const uint4*)&As[(mh + i * 16 + l16) * 32 + quad * 8]);
            bfv[i] = as_bf16x8(*(const uint4*)&Bs[(nh + i * 16 + l16) * 32 + quad * 8]);
        }
        #pragma unroll
        for (int i = 0; i < 4; i++)
            #pragma unroll
            for (int j = 0; j < 4; j++)
                acc[i][j] = __builtin_amdgcn_mfma_f32_16x16x32_bf16(af[i], bfv[j], acc[i][j], 0, 0, 0);
    }
    #pragma unroll
    for (int j = 0; j < 4; j++) {
        int gn = n0 + nh + j * 16 + l16;
        float bv = bias ? bias[gn] : 0.f;
        #pragma unroll
        for (int i = 0; i < 4; i++) {
            #pragma unroll
            for (int r = 0; r < 4; r++) {
                int gm = m0 + mh + i * 16 + quad * 4 + r;
                if (gm < M) {
                    float v = acc[i][j][r] + bv;
                    if constexpr (RESID) v += resid[(size_t)gm * N + gn];
                    if constexpr (__is_same(TC, u16)) C[(size_t)gm * N + gn] = f2bf(v);
                    else                              C[(size_t)gm * N + gn] = v;
                }
            }
        }
    }
}

// ---------------- Flash attention, S^T formulation, 128-key tiles ----------------
// Q pre-scaled by 0.125*log2(e) (folded into Wq). Per block: 64 q-rows, 4 waves x 16 rows.
// S^T = K·Q^T: lane l16 holds scores of q-row l16, keys quad*4+r per subtile (in regs).
__global__ __launch_bounds__(256) void attn_k(const u16* Q, const u16* __restrict__ K,
                                              const u16* __restrict__ V, u16* O, int S) {
    __shared__ __align__(16) u16 Ks[128][72];     // K tile [key][d], padded
    __shared__ __align__(16) u16 Vt[64][136];     // V^T tile [d][key], padded
    __shared__ __align__(16) u16 Pb[4][16][136];  // per-wave P [qrow][key]
    int bh = blockIdx.x;
    int b = bh >> 4, h = bh & 15;
    int q0 = blockIdx.y * 64;
    int t = threadIdx.x;
    int w = t >> 6, lane = t & 63;
    int quad = lane >> 4, l16 = lane & 15;
    const u16* Qp = Q + ((size_t)b * NTOK + q0) * DIM + h * DHEAD;
    const u16* Kp = K + (size_t)b * S * DIM + h * DHEAD;
    const u16* Vp = V + (size_t)b * S * DIM + h * DHEAD;
    bf16x8 qf[2];
    #pragma unroll
    for (int ds = 0; ds < 2; ds++)
        qf[ds] = as_bf16x8(*(const uint4*)(Qp + (size_t)(w * 16 + l16) * DIM + ds * 32 + quad * 8));
    float m_l = -1e30f;   // per-lane running max (log2 domain) for q-row l16
    float l_l = 0.f;      // per-lane partial denom (this quad's keys) for q-row l16
    f32x4 o_acc[4];       // [dt]: row quad*4+r = q-row, col l16 = d
    #pragma unroll
    for (int dt = 0; dt < 4; dt++) o_acc[dt] = f4zero();
    int vd = (t >> 5) * 8;   // V staging: d-base
    int vk = (t & 31) * 4;   // V staging: key-base
    int ku = t >> 1;                 // K staging: row
    int kp2 = (t & 1) * 32;          // K staging: col base (elems)
    int nkt = (S + 127) / 128;
    for (int kt = 0; kt < nkt; kt++) {
        int kbase = kt * 128;
        bool full = (kbase + 128) <= S;
        __syncthreads();
        {   // stage K [128][72]
            int krow = min(kbase + ku, S - 1);
            const u16* kg = Kp + (size_t)krow * DIM + kp2;
            uint4 k0 = *(const uint4*)(kg);
            uint4 k1 = *(const uint4*)(kg + 8);
            uint4 k2 = *(const uint4*)(kg + 16);
            uint4 k3 = *(const uint4*)(kg + 24);
            *(uint4*)&Ks[ku][kp2]      = k0;
            *(uint4*)&Ks[ku][kp2 + 8]  = k1;
            *(uint4*)&Ks[ku][kp2 + 16] = k2;
            *(uint4*)&Ks[ku][kp2 + 24] = k3;
        }
        {   // stage V transposed: 4 keys x 8 d per thread, b64 packed writes
            union { uint4 u; u16 e[8]; } vr[4];
            #pragma unroll
            for (int j = 0; j < 4; j++) {
                int key = min(kbase + vk + j, S - 1);
                vr[j].u = *(const uint4*)(Vp + (size_t)key * DIM + vd);
            }
            #pragma unroll
            for (int d = 0; d < 8; d++) {
                uint2 p;
                p.x = (unsigned)vr[0].e[d] | ((unsigned)vr[1].e[d] << 16);
                p.y = (unsigned)vr[2].e[d] | ((unsigned)vr[3].e[d] << 16);
                *(uint2*)&Vt[vd + d][vk] = p;
            }
        }
        __syncthreads();
        // S^T: 8 subtiles of 16 keys; mfma(A=K, B=Q) -> D[key][qrow]
        f32x4 sc[8];
        #pragma unroll
        for (int sub = 0; sub < 8; sub++) {
            bf16x8 kf0 = as_bf16x8(*(const uint4*)&Ks[sub * 16 + l16][quad * 8]);
            bf16x8 kf1 = as_bf16x8(*(const uint4*)&Ks[sub * 16 + l16][32 + quad * 8]);
            f32x4 s = __builtin_amdgcn_mfma_f32_16x16x32_bf16(kf0, qf[0], f4zero(), 0, 0, 0);
            sc[sub] = __builtin_amdgcn_mfma_f32_16x16x32_bf16(kf1, qf[1], s, 0, 0, 0);
        }
        // mask invalid keys (wave-uniform branch)
        if (!full) {
            #pragma unroll
            for (int sub = 0; sub < 8; sub++)
                #pragma unroll
                for (int r = 0; r < 4; r++)
                    if (kbase + sub * 16 + quad * 4 + r >= S) sc[sub][r] = -1e30f;
        }
        // per-lane max over 32 regs + 2 shuffle steps across quads
        float tmax = -1e30f;
        #pragma unroll
        for (int sub = 0; sub < 8; sub++)
            #pragma unroll
            for (int r = 0; r < 4; r++) tmax = fmaxf(tmax, sc[sub][r]);
        tmax = fmaxf(tmax, __shfl_xor(tmax, 16, 64));
        tmax = fmaxf(tmax, __shfl_xor(tmax, 32, 64));
        float mnew = fmaxf(m_l, tmax);
        float alpha = exp2f(m_l - mnew);
        m_l = mnew;
        // exp2 + pack P (bf16 truncation via v_perm) + per-lane partial sum
        float psum = 0.f;
        #pragma unroll
        for (int sub = 0; sub < 8; sub++) {
            float p0 = exp2f(sc[sub][0] - mnew);
            float p1 = exp2f(sc[sub][1] - mnew);
            float p2 = exp2f(sc[sub][2] - mnew);
            float p3 = exp2f(sc[sub][3] - mnew);
            psum += (p0 + p1) + (p2 + p3);
            uint2 pk;
            pk.x = __builtin_amdgcn_perm(__float_as_uint(p1), __float_as_uint(p0), 0x07060302);
            pk.y = __builtin_amdgcn_perm(__float_as_uint(p3), __float_as_uint(p2), 0x07060302);
            *(uint2*)&Pb[w][l16][sub * 16 + quad * 4] = pk;
        }
        l_l = l_l * alpha + psum;
        // broadcast alpha to o_acc rows (row quad*4+r holds q-row quad*4+r; alpha lives at lane = q-row)
        float a_r[4];
        #pragma unroll
        for (int r = 0; r < 4; r++) a_r[r] = __shfl(alpha, quad * 4 + r, 64);
        #pragma unroll
        for (int dt = 0; dt < 4; dt++)
            #pragma unroll
            for (int r = 0; r < 4; r++) o_acc[dt][r] *= a_r[r];
        // PV: A = P (own-wave LDS, waitcnt only), B = V^T (staged pre-barrier)
        #pragma unroll
        for (int kk = 0; kk < 4; kk++) {
            bf16x8 pf = as_bf16x8(*(const uint4*)&Pb[w][l16][kk * 32 + quad * 8]);
            #pragma unroll
            for (int dt = 0; dt < 4; dt++) {
                bf16x8 vf = as_bf16x8(*(const uint4*)&Vt[dt * 16 + l16][kk * 32 + quad * 8]);
                o_acc[dt] = __builtin_amdgcn_mfma_f32_16x16x32_bf16(pf, vf, o_acc[dt], 0, 0, 0);
            }
        }
    }
    // final denom: reduce per-lane partials across quads, broadcast to rows
    float l_tot = l_l;
    l_tot += __shfl_xor(l_tot, 16, 64);
    l_tot += __shfl_xor(l_tot, 32, 64);
    #pragma unroll
    for (int r = 0; r < 4; r++) {
        float lr = __shfl(l_tot, quad * 4 + r, 64);
        float invl = (lr > 0.f) ? (1.f / lr) : 0.f;
        int gq = q0 + w * 16 + quad * 4 + r;
        #pragma unroll
        for (int dt = 0; dt < 4; dt++) {
            O[((size_t)b * NTOK + gq) * DIM + h * DHEAD + dt * 16 + l16] = f2bf(o_acc[dt][r] * invl);
        }
    }
}

// ---------------- GEGLU ----------------
__global__ __launch_bounds__(256) void geglu_k(const u16* __restrict__ H, u16* __restrict__ G) {
    int c = blockIdx.x * 256 + threadIdx.x;
    size_t row = blockIdx.y;
    float a = bf2f(H[row * (2 * FFIN) + c]);
    float g = bf2f(H[row * (2 * FFIN) + FFIN + c]);
    float out = a * (0.5f * g * (1.f + erff(g * 0.70710678118654752f)));
    G[row * FFIN + c] = f2bf(out);
}

extern "C" void kernel_launch(void* const* d_in, const int* in_sizes, int n_in,
                              void* d_out, int out_size, void* d_ws, size_t ws_size,
                              hipStream_t stream) {
    const float* x   = (const float*)d_in[0];
    const float* ctx = (const float*)d_in[1];
    const float* Wq1 = (const float*)d_in[2];
    const float* Wk1 = (const float*)d_in[3];
    const float* Wv1 = (const float*)d_in[4];
    const float* Wo1 = (const float*)d_in[5];
    const float* bo1 = (const float*)d_in[6];
    const float* Wq2 = (const float*)d_in[7];
    const float* Wk2 = (const float*)d_in[8];
    const float* Wv2 = (const float*)d_in[9];
    const float* Wo2 = (const float*)d_in[10];
    const float* bo2 = (const float*)d_in[11];
    const float* Wp  = (const float*)d_in[12];
    const float* bp  = (const float*)d_in[13];
    const float* Wf  = (const float*)d_in[14];
    const float* bfb = (const float*)d_in[15];
    const float* g1  = (const float*)d_in[16];
    const float* b1  = (const float*)d_in[17];
    const float* g2  = (const float*)d_in[18];
    const float* b2  = (const float*)d_in[19];
    const float* g3  = (const float*)d_in[20];
    const float* b3  = (const float*)d_in[21];
    float* out = (float*)d_out;

    const int M = BATCH * NTOK;      // 8192
    const int Mc = BATCH * SCROSS;   // 308
    const size_t R = (size_t)M * DIM;
    u16* ws = (u16*)d_ws;
    size_t o = 0;
    u16* WqT1 = ws + o; o += (size_t)DIM * DIM;
    u16* WkT1 = ws + o; o += (size_t)DIM * DIM;
    u16* WvT1 = ws + o; o += (size_t)DIM * DIM;
    u16* WoT1 = ws + o; o += (size_t)DIM * DIM;
    u16* WqT2 = ws + o; o += (size_t)DIM * DIM;
    u16* WoT2 = ws + o; o += (size_t)DIM * DIM;
    u16* WkT2 = ws + o; o += (size_t)DIM * CTXD;
    u16* WvT2 = ws + o; o += (size_t)DIM * CTXD;
    u16* WpT  = ws + o; o += (size_t)(2 * FFIN) * DIM;
    u16* WfT  = ws + o; o += (size_t)DIM * FFIN;
    u16* ctxb = ws + o; o += (size_t)Mc * CTXD;
    u16* Kc   = ws + o; o += (size_t)Mc * DIM;
    u16* Vc   = ws + o; o += (size_t)Mc * DIM;
    u16* P    = ws + o; o += R;
    u16* Qb   = ws + o; o += R;
    u16* reg2 = ws + o; o += 2 * R;   // Ks,Vs -> X1(fp32) -> hb
    u16* Ks = reg2;
    u16* Vs = reg2 + R;
    float* X1 = (float*)reg2;
    u16* hb = reg2;
    size_t base_elems = o;
    size_t gbfull_elems = (size_t)M * FFIN;
    bool planA = ws_size >= (base_elems + gbfull_elems) * sizeof(u16);
    u16* gbF = ws + base_elems;  // plan A only

    dim3 blk(256);
    const float qscale = 0.125f * 1.4426950408889634f;  // 1/sqrt(64) * log2(e), folded into Wq

    // --- weight conversions (fp32 -> bf16, transposed to [N][K]) ---
    wt_k<<<dim3(16, 16), blk, 0, stream>>>(Wq1, WqT1, DIM, DIM, qscale);
    wt_k<<<dim3(16, 16), blk, 0, stream>>>(Wk1, WkT1, DIM, DIM, 1.f);
    wt_k<<<dim3(16, 16), blk, 0, stream>>>(Wv1, WvT1, DIM, DIM, 1.f);
    wt_k<<<dim3(16, 16), blk, 0, stream>>>(Wo1, WoT1, DIM, DIM, 1.f);
    wt_k<<<dim3(16, 16), blk, 0, stream>>>(Wq2, WqT2, DIM, DIM, qscale);
    wt_k<<<dim3(16, 16), blk, 0, stream>>>(Wo2, WoT2, DIM, DIM, 1.f);
    wt_k<<<dim3(12, 16), blk, 0, stream>>>(Wk2, WkT2, CTXD, DIM, 1.f);
    wt_k<<<dim3(12, 16), blk, 0, stream>>>(Wv2, WvT2, CTXD, DIM, 1.f);
    wt_k<<<dim3(16, 128), blk, 0, stream>>>(Wp, WpT, DIM, 2 * FFIN, 1.f);
    wt_k<<<dim3(64, 16), blk, 0, stream>>>(Wf, WfT, FFIN, DIM, 1.f);
    cvt_k<<<dim3((Mc * CTXD / 4 + 255) / 256), blk, 0, stream>>>(ctx, ctxb, Mc * CTXD / 4);

    // --- self attention ---
    ln_k<<<dim3(M), blk, 0, stream>>>(x, g1, b1, P);
    gemm128<u16, false><<<dim3(M / 128, DIM / 128), blk, 0, stream>>>(P, WqT1, nullptr, nullptr, Qb, M, DIM, DIM);
    gemm128<u16, false><<<dim3(M / 128, DIM / 128), blk, 0, stream>>>(P, WkT1, nullptr, nullptr, Ks, M, DIM, DIM);
    gemm128<u16, false><<<dim3(M / 128, DIM / 128), blk, 0, stream>>>(P, WvT1, nullptr, nullptr, Vs, M, DIM, DIM);
    attn_k<<<dim3(BATCH * HEADS, NTOK / 64), blk, 0, stream>>>(Qb, Ks, Vs, Qb, NTOK);
    gemm128<float, true><<<dim3(M / 128, DIM / 128), blk, 0, stream>>>(Qb, WoT1, bo1, x, X1, M, DIM, DIM);

    // --- cross attention ---
    ln_k<<<dim3(M), blk, 0, stream>>>(X1, g2, b2, P);
    gemm128<u16, false><<<dim3(M / 128, DIM / 128), blk, 0, stream>>>(P, WqT2, nullptr, nullptr, Qb, M, DIM, DIM);
    gemm128<u16, false><<<dim3((Mc + 127) / 128, DIM / 128), blk, 0, stream>>>(ctxb, WkT2, nullptr, nullptr, Kc, Mc, DIM, CTXD);
    gemm128<u16, false><<<dim3((Mc + 127) / 128, DIM / 128), blk, 0, stream>>>(ctxb, WvT2, nullptr, nullptr, Vc, Mc, DIM, CTXD);
    attn_k<<<dim3(BATCH * HEADS, NTOK / 64), blk, 0, stream>>>(Qb, Kc, Vc, Qb, SCROSS);
    gemm128<float, true><<<dim3(M / 128, DIM / 128), blk, 0, stream>>>(Qb, WoT2, bo2, X1, out, M, DIM, DIM);

    // --- GEGLU FF ---
    ln_k<<<dim3(M), blk, 0, stream>>>(out, g3, b3, P);
    if (planA) {
        const int CH = 2048;
        for (int c0 = 0; c0 < M; c0 += CH) {
            gemm128<u16, false><<<dim3(CH / 128, (2 * FFIN) / 128), blk, 0, stream>>>(
                P + (size_t)c0 * DIM, WpT, bp, nullptr, hb, CH, 2 * FFIN, DIM);
            geglu_k<<<dim3(FFIN / 256, CH), blk, 0, stream>>>(hb, gbF + (size_t)c0 * FFIN);
        }
        gemm128<float, true><<<dim3(M / 128, DIM / 128), blk, 0, stream>>>(
            gbF, WfT, bfb, out, out, M, DIM, FFIN);
    } else {
        const int CH = 1024;
        u16* gb = reg2 + (size_t)CH * (2 * FFIN);
        for (int c0 = 0; c0 < M; c0 += CH) {
            gemm128<u16, false><<<dim3(CH / 128, (2 * FFIN) / 128), blk, 0, stream>>>(
                P + (size_t)c0 * DIM, WpT, bp, nullptr, hb, CH, 2 * FFIN, DIM);
            geglu_k<<<dim3(FFIN / 256, CH), blk, 0, stream>>>(hb, gb);
            gemm128<float, true><<<dim3(CH / 128, DIM / 128), blk, 0, stream>>>(
                gb, WfT, bfb, out + (size_t)c0 * DIM, out + (size_t)c0 * DIM, CH, DIM, FFIN);
        }
    }
}

// Round 5
// 934.411 us; speedup vs baseline: 3.2068x; 1.2160x over previous
//
#include <hip/hip_runtime.h>

typedef unsigned short u16;
typedef __bf16 bf16x8 __attribute__((ext_vector_type(8)));
typedef float f32x4 __attribute__((ext_vector_type(4)));

#define HEADS 16
#define DHEAD 64
#define DIM 1024
#define NTOK 2048
#define BATCH 4
#define CTXD 768
#define SCROSS 77
#define FFIN 4096

__device__ inline float bf2f(u16 v) { return __uint_as_float(((unsigned)v) << 16); }
__device__ inline u16 f2bf(float f) {
    unsigned u = __float_as_uint(f);
    unsigned r = u + 0x7fffu + ((u >> 16) & 1u);
    return (u16)(r >> 16);
}
__device__ inline f32x4 f4zero() { f32x4 v; v[0]=0.f; v[1]=0.f; v[2]=0.f; v[3]=0.f; return v; }
__device__ inline bf16x8 as_bf16x8(uint4 u) { union { uint4 a; bf16x8 b; } c; c.a = u; return c.b; }

// async global->LDS, 16B per lane; per-lane global gather, LDS dest = wave base + lane*16
__device__ inline void gload_lds16(const u16* g, u16* l) {
    __builtin_amdgcn_global_load_lds((const __attribute__((address_space(1))) unsigned*)g,
                                     (__attribute__((address_space(3))) unsigned*)l, 16, 0, 0);
}

// ---------------- weight convert+transpose: W[K][N] fp32 -> WT[N][K] bf16 (xscale) ----------------
__global__ __launch_bounds__(256) void wt_k(const float* __restrict__ W, u16* __restrict__ WT,
                                            int K, int N, float scale) {
    __shared__ u16 Ts[64][72];
    int k0 = blockIdx.x * 64, n0 = blockIdx.y * 64;
    int t = threadIdx.x;
    int r = t >> 2, c4 = (t & 3) * 16;
    const float* wp = W + (size_t)(k0 + r) * N + n0 + c4;
    #pragma unroll
    for (int j = 0; j < 4; j++) {
        float4 v = *(const float4*)(wp + j * 4);
        Ts[c4 + j * 4 + 0][r] = f2bf(v.x * scale);
        Ts[c4 + j * 4 + 1][r] = f2bf(v.y * scale);
        Ts[c4 + j * 4 + 2][r] = f2bf(v.z * scale);
        Ts[c4 + j * 4 + 3][r] = f2bf(v.w * scale);
    }
    __syncthreads();
    int n = t >> 2, kc = (t & 3) * 16;
    u16* op = WT + (size_t)(n0 + n) * K + k0 + kc;
    *(uint4*)op       = *(const uint4*)&Ts[n][kc];
    *(uint4*)(op + 8) = *(const uint4*)&Ts[n][kc + 8];
}

// ---------------- fp32 -> bf16 convert (ctx) ----------------
__global__ __launch_bounds__(256) void cvt_k(const float* __restrict__ X, u16* __restrict__ Y, int n4) {
    int i = blockIdx.x * 256 + threadIdx.x;
    if (i < n4) {
        float4 v = *(const float4*)(X + (size_t)i * 4);
        uint2 o;
        o.x = (unsigned)f2bf(v.x) | ((unsigned)f2bf(v.y) << 16);
        o.y = (unsigned)f2bf(v.z) | ((unsigned)f2bf(v.w) << 16);
        *(uint2*)(Y + (size_t)i * 4) = o;
    }
}

// ---------------- LayerNorm: fp32 in, bf16 out. One block per row of 1024. ----------------
__global__ __launch_bounds__(256) void ln_k(const float* __restrict__ X, const float* __restrict__ G,
                                            const float* __restrict__ Bt, u16* __restrict__ Y) {
    int row = blockIdx.x;
    int t = threadIdx.x;
    int w = t >> 6, lane = t & 63;
    float4 xv = *(const float4*)(X + (size_t)row * DIM + t * 4);
    float s = xv.x + xv.y + xv.z + xv.w;
    float s2 = xv.x*xv.x + xv.y*xv.y + xv.z*xv.z + xv.w*xv.w;
    for (int off = 1; off < 64; off <<= 1) {
        s  += __shfl_xor(s,  off, 64);
        s2 += __shfl_xor(s2, off, 64);
    }
    __shared__ float rs[4], rs2[4];
    if (lane == 0) { rs[w] = s; rs2[w] = s2; }
    __syncthreads();
    float S_ = rs[0] + rs[1] + rs[2] + rs[3];
    float S2_ = rs2[0] + rs2[1] + rs2[2] + rs2[3];
    float mean = S_ * (1.0f / DIM);
    float var = fmaxf(S2_ * (1.0f / DIM) - mean * mean, 0.f);
    float rstd = rsqrtf(var + 1e-5f);
    int col = t * 4;
    float4 g = *(const float4*)(G + col);
    float4 b = *(const float4*)(Bt + col);
    float y0 = (xv.x - mean) * rstd * g.x + b.x;
    float y1 = (xv.y - mean) * rstd * g.y + b.y;
    float y2 = (xv.z - mean) * rstd * g.z + b.z;
    float y3 = (xv.w - mean) * rstd * g.w + b.w;
    uint2 o;
    o.x = (unsigned)f2bf(y0) | ((unsigned)f2bf(y1) << 16);
    o.y = (unsigned)f2bf(y2) | ((unsigned)f2bf(y3) << 16);
    *(uint2*)(Y + (size_t)row * DIM + col) = o;
}

// ---------------- GEMM m97-style: C[M,N] = A[M,K] (ld lda) * BT[N,K]^T (+bias +resid) ----------------
// 128x128 tile, BK=32, 256 thr = 4 waves. resid (if used) has ld == N.
template<typename TC, bool RESID>
__global__ __launch_bounds__(256) void gemm128(const u16* __restrict__ A, int lda,
                                               const u16* __restrict__ BT,
                                               const float* __restrict__ bias, const float* resid,
                                               TC* C, int ldc, int M, int N, int K) {
    __shared__ __align__(16) u16 As[128 * 32];
    __shared__ __align__(16) u16 Bs[128 * 32];
    int m0 = blockIdx.x * 128, n0 = blockIdx.y * 128;
    int t = threadIdx.x;
    int w = t >> 6, lane = t & 63;
    int quad = lane >> 4, l16 = lane & 15;
    int mh = (w & 1) * 64, nh = (w >> 1) * 64;
    f32x4 acc[4][4];
    #pragma unroll
    for (int i = 0; i < 4; i++)
        #pragma unroll
        for (int j = 0; j < 4; j++) acc[i][j] = f4zero();
    int sr = t >> 2;
    int sc8 = (t & 3) * 8;
    int ra0 = min(m0 + sr, M - 1);
    int ra1 = min(m0 + sr + 64, M - 1);
    const u16* ga0 = A + (size_t)ra0 * lda + sc8;
    const u16* ga1 = A + (size_t)ra1 * lda + sc8;
    const u16* gb0 = BT + (size_t)(n0 + sr) * K + sc8;
    const u16* gb1 = BT + (size_t)(n0 + sr + 64) * K + sc8;
    u16* lA0 = &As[w * 512];
    u16* lA1 = &As[2048 + w * 512];
    u16* lB0 = &Bs[w * 512];
    u16* lB1 = &Bs[2048 + w * 512];
    for (int k0 = 0; k0 < K; k0 += 32) {
        __syncthreads();
        gload_lds16(ga0 + k0, lA0);
        gload_lds16(ga1 + k0, lA1);
        gload_lds16(gb0 + k0, lB0);
        gload_lds16(gb1 + k0, lB1);
        __syncthreads();
        bf16x8 af[4], bfv[4];
        #pragma unroll
        for (int i = 0; i < 4; i++) {
            af[i]  = as_bf16x8(*(const uint4*)&As[(mh + i * 16 + l16) * 32 + quad * 8]);
            bfv[i] = as_bf16x8(*(const uint4*)&Bs[(nh + i * 16 + l16) * 32 + quad * 8]);
        }
        #pragma unroll
        for (int i = 0; i < 4; i++)
            #pragma unroll
            for (int j = 0; j < 4; j++)
                acc[i][j] = __builtin_amdgcn_mfma_f32_16x16x32_bf16(af[i], bfv[j], acc[i][j], 0, 0, 0);
    }
    #pragma unroll
    for (int j = 0; j < 4; j++) {
        int gn = n0 + nh + j * 16 + l16;
        float bv = bias ? bias[gn] : 0.f;
        #pragma unroll
        for (int i = 0; i < 4; i++) {
            #pragma unroll
            for (int r = 0; r < 4; r++) {
                int gm = m0 + mh + i * 16 + quad * 4 + r;
                if (gm < M) {
                    float v = acc[i][j][r] + bv;
                    if constexpr (RESID) v += resid[(size_t)gm * N + gn];
                    if constexpr (__is_same(TC, u16)) C[(size_t)gm * ldc + gn] = f2bf(v);
                    else                              C[(size_t)gm * ldc + gn] = v;
                }
            }
        }
    }
}

// ---------------- fused Wp GEMM + GEGLU: Gb = (A*Wp_a + bp_a) * gelu(A*Wp_g + bp_g) ----------------
// grid (M/128, FFIN/128). BT = WpT[8192][1024]: a-rows = n0.., gate-rows = 4096+n0..
__global__ __launch_bounds__(256, 2) void gemm_geglu(const u16* __restrict__ A,
                                                     const u16* __restrict__ BT,
                                                     const float* __restrict__ bp,
                                                     u16* __restrict__ Gb, int M) {
    __shared__ __align__(16) u16 As[128 * 32];
    __shared__ __align__(16) u16 Bs1[128 * 32];
    __shared__ __align__(16) u16 Bs2[128 * 32];
    const int K = DIM;
    int m0 = blockIdx.x * 128, n0 = blockIdx.y * 128;
    int t = threadIdx.x;
    int w = t >> 6, lane = t & 63;
    int quad = lane >> 4, l16 = lane & 15;
    int mh = (w & 1) * 64, nh = (w >> 1) * 64;
    f32x4 acc1[4][4], acc2[4][4];
    #pragma unroll
    for (int i = 0; i < 4; i++)
        #pragma unroll
        for (int j = 0; j < 4; j++) { acc1[i][j] = f4zero(); acc2[i][j] = f4zero(); }
    int sr = t >> 2;
    int sc8 = (t & 3) * 8;
    const u16* ga0 = A + (size_t)(m0 + sr) * K + sc8;
    const u16* ga1 = A + (size_t)(m0 + sr + 64) * K + sc8;
    const u16* gb0 = BT + (size_t)(n0 + sr) * K + sc8;
    const u16* gb1 = BT + (size_t)(n0 + sr + 64) * K + sc8;
    const u16* gc0 = BT + (size_t)(FFIN + n0 + sr) * K + sc8;
    const u16* gc1 = BT + (size_t)(FFIN + n0 + sr + 64) * K + sc8;
    u16* lA0 = &As[w * 512];
    u16* lA1 = &As[2048 + w * 512];
    u16* lB0 = &Bs1[w * 512];
    u16* lB1 = &Bs1[2048 + w * 512];
    u16* lC0 = &Bs2[w * 512];
    u16* lC1 = &Bs2[2048 + w * 512];
    for (int k0 = 0; k0 < K; k0 += 32) {
        __syncthreads();
        gload_lds16(ga0 + k0, lA0);
        gload_lds16(ga1 + k0, lA1);
        gload_lds16(gb0 + k0, lB0);
        gload_lds16(gb1 + k0, lB1);
        gload_lds16(gc0 + k0, lC0);
        gload_lds16(gc1 + k0, lC1);
        __syncthreads();
        bf16x8 af[4];
        #pragma unroll
        for (int i = 0; i < 4; i++)
            af[i] = as_bf16x8(*(const uint4*)&As[(mh + i * 16 + l16) * 32 + quad * 8]);
        #pragma unroll
        for (int j = 0; j < 4; j++) {
            bf16x8 b1 = as_bf16x8(*(const uint4*)&Bs1[(nh + j * 16 + l16) * 32 + quad * 8]);
            bf16x8 b2 = as_bf16x8(*(const uint4*)&Bs2[(nh + j * 16 + l16) * 32 + quad * 8]);
            #pragma unroll
            for (int i = 0; i < 4; i++) {
                acc1[i][j] = __builtin_amdgcn_mfma_f32_16x16x32_bf16(af[i], b1, acc1[i][j], 0, 0, 0);
                acc2[i][j] = __builtin_amdgcn_mfma_f32_16x16x32_bf16(af[i], b2, acc2[i][j], 0, 0, 0);
            }
        }
    }
    #pragma unroll
    for (int j = 0; j < 4; j++) {
        int gn = n0 + nh + j * 16 + l16;
        float b1v = bp[gn];
        float b2v = bp[FFIN + gn];
        #pragma unroll
        for (int i = 0; i < 4; i++) {
            #pragma unroll
            for (int r = 0; r < 4; r++) {
                int gm = m0 + mh + i * 16 + quad * 4 + r;
                float a = acc1[i][j][r] + b1v;
                float g = acc2[i][j][r] + b2v;
                float v = a * (0.5f * g * (1.f + erff(g * 0.70710678118654752f)));
                Gb[(size_t)gm * FFIN + gn] = f2bf(v);
            }
        }
    }
}

// ---------------- Flash attention v2: max-free log2-softmax, stride-32 LDS tiles ----------------
// Q pre-scaled by 0.125*log2(e) (folded into Wq). Block = (b,h) x 64 q-rows, 4 waves x 16 rows.
// Q/O stride ldq, K/V stride ldkv. O==Q in-place safe.
__global__ __launch_bounds__(256) void attn_k(const u16* Q, int ldq, const u16* __restrict__ K,
                                              const u16* __restrict__ V, int ldkv,
                                              u16* O, int S) {
    __shared__ __align__(16) u16 Ksh[2][4096];    // d-halves: [128 keys][32 d], stride 32
    __shared__ __align__(16) u16 Vt[4][2048];     // key-chunks: [64 d][32 keys], stride 32
    __shared__ __align__(16) u16 Pb[4][4][512];   // [wave][key-chunk][16 qrow][32 keys]
    int bh = blockIdx.x;
    int b = bh >> 4, h = bh & 15;
    int q0 = blockIdx.y * 64;
    int t = threadIdx.x;
    int w = t >> 6, lane = t & 63;
    int quad = lane >> 4, l16 = lane & 15;
    const u16* Qp = Q + ((size_t)b * NTOK + q0) * ldq + h * DHEAD;
    const u16* Kp = K + (size_t)b * S * ldkv + h * DHEAD;
    const u16* Vp = V + (size_t)b * S * ldkv + h * DHEAD;
    bf16x8 qf[2];
    #pragma unroll
    for (int ds = 0; ds < 2; ds++)
        qf[ds] = as_bf16x8(*(const uint4*)(Qp + (size_t)(w * 16 + l16) * ldq + ds * 32 + quad * 8));
    float l_l = 0.f;      // per-lane partial denom for q-row l16 (this quad's keys)
    f32x4 o_acc[4];
    #pragma unroll
    for (int dt = 0; dt < 4; dt++) o_acc[dt] = f4zero();
    // K staging gather mapping: chunk c (16B) -> key row c>>2, d-offset (c&3)*8; wave w: chunks [w*128, +128)
    int cA = w * 128 + lane;
    int krA = cA >> 2, kdA = (cA & 3) * 8;
    int krB = (cA + 64) >> 2, kdB = ((cA + 64) & 3) * 8;
    // V staging: thread handles 4 keys x 8 d
    int vd = (t >> 5) * 8;
    int vk = (t & 31) * 4;
    int vkk = vk >> 5, vcol = vk & 31;
    int nkt = (S + 127) / 128;
    for (int kt = 0; kt < nkt; kt++) {
        int kbase = kt * 128;
        bool full = (kbase + 128) <= S;
        __syncthreads();
        {   // stage K async (per-lane gather, conflict-free stride-32 LDS layout)
            int rA = min(kbase + krA, S - 1);
            int rB = min(kbase + krB, S - 1);
            const u16* kgA = Kp + (size_t)rA * ldkv;
            const u16* kgB = Kp + (size_t)rB * ldkv;
            gload_lds16(kgA + kdA,      &Ksh[0][w * 1024]);
            gload_lds16(kgB + kdB,      &Ksh[0][w * 1024 + 512]);
            gload_lds16(kgA + 32 + kdA, &Ksh[1][w * 1024]);
            gload_lds16(kgB + 32 + kdB, &Ksh[1][w * 1024 + 512]);
        }
        {   // stage V transposed
            union { uint4 u; u16 e[8]; } vr[4];
            #pragma unroll
            for (int j = 0; j < 4; j++) {
                int key = min(kbase + vk + j, S - 1);
                vr[j].u = *(const uint4*)(Vp + (size_t)key * ldkv + vd);
            }
            #pragma unroll
            for (int d = 0; d < 8; d++) {
                uint2 p;
                p.x = (unsigned)vr[0].e[d] | ((unsigned)vr[1].e[d] << 16);
                p.y = (unsigned)vr[2].e[d] | ((unsigned)vr[3].e[d] << 16);
                *(uint2*)&Vt[vkk][(vd + d) * 32 + vcol] = p;
            }
        }
        __syncthreads();
        // S^T = K·Q^T: 8 subtiles of 16 keys; D[key][qrow]
        f32x4 sc[8];
        #pragma unroll
        for (int sub = 0; sub < 8; sub++) {
            bf16x8 kf0 = as_bf16x8(*(const uint4*)&Ksh[0][(sub * 16 + l16) * 32 + quad * 8]);
            bf16x8 kf1 = as_bf16x8(*(const uint4*)&Ksh[1][(sub * 16 + l16) * 32 + quad * 8]);
            f32x4 s = __builtin_amdgcn_mfma_f32_16x16x32_bf16(kf0, qf[0], f4zero(), 0, 0, 0);
            sc[sub] = __builtin_amdgcn_mfma_f32_16x16x32_bf16(kf1, qf[1], s, 0, 0, 0);
        }
        if (!full) {
            #pragma unroll
            for (int sub = 0; sub < 8; sub++)
                #pragma unroll
                for (int r = 0; r < 4; r++)
                    if (kbase + sub * 16 + quad * 4 + r >= S) sc[sub][r] = -1e30f;
        }
        // max-free: p = exp2(s) directly (log2-domain scores; common scale cancels in o/l)
        float psum = 0.f;
        #pragma unroll
        for (int sub = 0; sub < 8; sub++) {
            float p0 = __builtin_amdgcn_exp2f(sc[sub][0]);
            float p1 = __builtin_amdgcn_exp2f(sc[sub][1]);
            float p2 = __builtin_amdgcn_exp2f(sc[sub][2]);
            float p3 = __builtin_amdgcn_exp2f(sc[sub][3]);
            psum += (p0 + p1) + (p2 + p3);
            uint2 pk;
            pk.x = __builtin_amdgcn_perm(__float_as_uint(p1), __float_as_uint(p0), 0x07060302);
            pk.y = __builtin_amdgcn_perm(__float_as_uint(p3), __float_as_uint(p2), 0x07060302);
            *(uint2*)&Pb[w][sub >> 1][l16 * 32 + (sub & 1) * 16 + quad * 4] = pk;
        }
        l_l += psum;
        // PV: P[16q x 128k] (A, own-wave LDS) x V^T (B)
        #pragma unroll
        for (int kk = 0; kk < 4; kk++) {
            bf16x8 pf = as_bf16x8(*(const uint4*)&Pb[w][kk][l16 * 32 + quad * 8]);
            #pragma unroll
            for (int dt = 0; dt < 4; dt++) {
                bf16x8 vf = as_bf16x8(*(const uint4*)&Vt[kk][(dt * 16 + l16) * 32 + quad * 8]);
                o_acc[dt] = __builtin_amdgcn_mfma_f32_16x16x32_bf16(pf, vf, o_acc[dt], 0, 0, 0);
            }
        }
    }
    float l_tot = l_l;
    l_tot += __shfl_xor(l_tot, 16, 64);
    l_tot += __shfl_xor(l_tot, 32, 64);
    #pragma unroll
    for (int r = 0; r < 4; r++) {
        float lr = __shfl(l_tot, quad * 4 + r, 64);
        float invl = (lr > 0.f) ? (1.f / lr) : 0.f;
        int gq = q0 + w * 16 + quad * 4 + r;
        #pragma unroll
        for (int dt = 0; dt < 4; dt++) {
            O[((size_t)b * NTOK + gq) * ldq + h * DHEAD + dt * 16 + l16] = f2bf(o_acc[dt][r] * invl);
        }
    }
}

extern "C" void kernel_launch(void* const* d_in, const int* in_sizes, int n_in,
                              void* d_out, int out_size, void* d_ws, size_t ws_size,
                              hipStream_t stream) {
    const float* x   = (const float*)d_in[0];
    const float* ctx = (const float*)d_in[1];
    const float* Wq1 = (const float*)d_in[2];
    const float* Wk1 = (const float*)d_in[3];
    const float* Wv1 = (const float*)d_in[4];
    const float* Wo1 = (const float*)d_in[5];
    const float* bo1 = (const float*)d_in[6];
    const float* Wq2 = (const float*)d_in[7];
    const float* Wk2 = (const float*)d_in[8];
    const float* Wv2 = (const float*)d_in[9];
    const float* Wo2 = (const float*)d_in[10];
    const float* bo2 = (const float*)d_in[11];
    const float* Wp  = (const float*)d_in[12];
    const float* bp  = (const float*)d_in[13];
    const float* Wf  = (const float*)d_in[14];
    const float* bfb = (const float*)d_in[15];
    const float* g1  = (const float*)d_in[16];
    const float* b1  = (const float*)d_in[17];
    const float* g2  = (const float*)d_in[18];
    const float* b2  = (const float*)d_in[19];
    const float* g3  = (const float*)d_in[20];
    const float* b3  = (const float*)d_in[21];
    float* out = (float*)d_out;

    const int M = BATCH * NTOK;      // 8192
    const int Mc = BATCH * SCROSS;   // 308
    u16* ws = (u16*)d_ws;
    size_t o = 0;
    u16* WqT1 = ws + o; o += (size_t)DIM * DIM;        // contiguous QKV weight stack:
    u16* WkT1 = ws + o; o += (size_t)DIM * DIM;
    u16* WvT1 = ws + o; o += (size_t)DIM * DIM;
    u16* WoT1 = ws + o; o += (size_t)DIM * DIM;
    u16* WqT2 = ws + o; o += (size_t)DIM * DIM;
    u16* WoT2 = ws + o; o += (size_t)DIM * DIM;
    u16* WkT2 = ws + o; o += (size_t)DIM * CTXD;       // contiguous KV2 stack
    u16* WvT2 = ws + o; o += (size_t)DIM * CTXD;
    u16* WpT  = ws + o; o += (size_t)(2 * FFIN) * DIM;
    u16* WfT  = ws + o; o += (size_t)DIM * FFIN;
    u16* ctxb = ws + o; o += (size_t)Mc * CTXD;
    u16* KVc  = ws + o; o += (size_t)Mc * 2048;        // cross K|V, ld 2048
    u16* P    = ws + o; o += (size_t)M * DIM;          // LN outputs
    u16* QKV  = ws + o; o += (size_t)M * 3072;         // Q|K|V / attn-out, ld 3072
    u16* reg2 = ws + o; o += (size_t)M * DIM * 2;      // X1 (fp32) ; tail of gb
    float* X1 = (float*)reg2;
    u16* gb = QKV;                                     // [8192][4096] overlays QKV+first half of reg2

    dim3 blk(256);
    const float qscale = 0.125f * 1.4426950408889634f;  // 1/sqrt(64) * log2(e)

    wt_k<<<dim3(16, 16), blk, 0, stream>>>(Wq1, WqT1, DIM, DIM, qscale);
    wt_k<<<dim3(16, 16), blk, 0, stream>>>(Wk1, WkT1, DIM, DIM, 1.f);
    wt_k<<<dim3(16, 16), blk, 0, stream>>>(Wv1, WvT1, DIM, DIM, 1.f);
    wt_k<<<dim3(16, 16), blk, 0, stream>>>(Wo1, WoT1, DIM, DIM, 1.f);
    wt_k<<<dim3(16, 16), blk, 0, stream>>>(Wq2, WqT2, DIM, DIM, qscale);
    wt_k<<<dim3(16, 16), blk, 0, stream>>>(Wo2, WoT2, DIM, DIM, 1.f);
    wt_k<<<dim3(12, 16), blk, 0, stream>>>(Wk2, WkT2, CTXD, DIM, 1.f);
    wt_k<<<dim3(12, 16), blk, 0, stream>>>(Wv2, WvT2, CTXD, DIM, 1.f);
    wt_k<<<dim3(16, 128), blk, 0, stream>>>(Wp, WpT, DIM, 2 * FFIN, 1.f);
    wt_k<<<dim3(64, 16), blk, 0, stream>>>(Wf, WfT, FFIN, DIM, 1.f);
    cvt_k<<<dim3((Mc * CTXD / 4 + 255) / 256), blk, 0, stream>>>(ctx, ctxb, Mc * CTXD / 4);

    // --- self attention ---
    ln_k<<<dim3(M), blk, 0, stream>>>(x, g1, b1, P);
    gemm128<u16, false><<<dim3(M / 128, 3072 / 128), blk, 0, stream>>>(
        P, DIM, WqT1, nullptr, nullptr, QKV, 3072, M, 3072, DIM);
    attn_k<<<dim3(BATCH * HEADS, NTOK / 64), blk, 0, stream>>>(
        QKV, 3072, QKV + 1024, QKV + 2048, 3072, QKV, NTOK);
    gemm128<float, true><<<dim3(M / 128, DIM / 128), blk, 0, stream>>>(
        QKV, 3072, WoT1, bo1, x, X1, DIM, M, DIM, DIM);

    // --- cross attention ---
    ln_k<<<dim3(M), blk, 0, stream>>>(X1, g2, b2, P);
    gemm128<u16, false><<<dim3(M / 128, DIM / 128), blk, 0, stream>>>(
        P, DIM, WqT2, nullptr, nullptr, QKV, 3072, M, DIM, DIM);
    gemm128<u16, false><<<dim3((Mc + 127) / 128, 2048 / 128), blk, 0, stream>>>(
        ctxb, CTXD, WkT2, nullptr, nullptr, KVc, 2048, Mc, 2048, CTXD);
    attn_k<<<dim3(BATCH * HEADS, NTOK / 64), blk, 0, stream>>>(
        QKV, 3072, KVc, KVc + 1024, 2048, QKV, SCROSS);
    gemm128<float, true><<<dim3(M / 128, DIM / 128), blk, 0, stream>>>(
        QKV, 3072, WoT2, bo2, X1, out, DIM, M, DIM, DIM);

    // --- GEGLU FF (fused Wp+geglu -> gb, then Wf with residual) ---
    ln_k<<<dim3(M), blk, 0, stream>>>(out, g3, b3, P);
    gemm_geglu<<<dim3(M / 128, FFIN / 128), blk, 0, stream>>>(P, WpT, bp, gb, M);
    gemm128<float, true><<<dim3(M / 128, DIM / 128), blk, 0, stream>>>(
        gb, FFIN, WfT, bfb, out, out, DIM, M, DIM, FFIN);
}